// Round 1
// 614.565 us; speedup vs baseline: 1.5922x; 1.5922x over previous
//
#include <hip/hip_runtime.h>

typedef unsigned short u16;
typedef unsigned int u32;

#define T_ 768
#define D_ 24
#define S_ 576
#define Q_ 32
#define K_ 128
#define CA_ 128
#define CP_ 16
#define CT_ 384
#define H_ 4
#define DH_ 32
#define SQ_ (S_*Q_)
#define SK_ (S_*K_)

__device__ __forceinline__ float b2f(u16 u){ return __uint_as_float(((u32)u)<<16); }
__device__ __forceinline__ u16 f2b(float f){ u32 x=__float_as_uint(f); return (u16)((x + 0x7fffu + ((x>>16)&1u))>>16); }

// ---- N1: per-atom conditioning gathered to query slots; also qrp/quid ----
__global__ __launch_bounds__(128) void n_qsc(
    const float* __restrict__ pos, const float* __restrict__ rmask, const float* __restrict__ charge,
    const float* __restrict__ amask, const int* __restrict__ elem, const int* __restrict__ chars,
    const int* __restrict__ uid, const int* __restrict__ t2q,
    const float* __restrict__ w_pos, const float* __restrict__ w_mask, const float* __restrict__ w_elem,
    const float* __restrict__ w_chg, const float* __restrict__ w_name,
    float* __restrict__ qsc, float* __restrict__ qmask, float* __restrict__ qrp, int* __restrict__ quid,
    float* __restrict__ out_qsc, float* __restrict__ out_qmask)
{
  int slot = blockIdx.x, ch = threadIdx.x;
  int a = t2q[slot];
  float p0 = pos[a*3+0], p1 = pos[a*3+1], p2 = pos[a*3+2];
  float m  = rmask[a];
  float cg = asinhf(charge[a]);
  int e  = elem[a];
  int c0 = chars[a*4+0], c1 = chars[a*4+1], c2 = chars[a*4+2], c3 = chars[a*4+3];
  float v = p0*w_pos[0*CA_+ch] + p1*w_pos[1*CA_+ch] + p2*w_pos[2*CA_+ch];
  v += m * w_mask[ch];
  v += w_elem[e*CA_+ch];
  v += cg * w_chg[ch];
  v += w_name[(0*64+c0)*CA_+ch] + w_name[(1*64+c1)*CA_+ch]
     + w_name[(2*64+c2)*CA_+ch] + w_name[(3*64+c3)*CA_+ch];
  v *= m;
  qsc[(size_t)slot*CA_+ch] = v;
  out_qsc[(size_t)slot*CA_+ch] = v;
  if (ch < 3) qrp[slot*3+ch] = pos[a*3+ch];
  if (ch == 0){
    float am = amask[a];
    qmask[slot] = am;
    out_qmask[slot] = am;
    quid[slot] = uid[a];
  }
}

// ---- N2: key-space gathers (ksc, kmask outputs; krp; kuid = uid[q2k] DIRECT) ----
__global__ __launch_bounds__(128) void n_keys(
    const float* __restrict__ qsc, const float* __restrict__ qmask, const float* __restrict__ qrp,
    const int* __restrict__ uid, const int* __restrict__ q2k,
    float* __restrict__ krp, int* __restrict__ kuid,
    float* __restrict__ out_ksc, float* __restrict__ out_kmask)
{
  int sk = blockIdx.x, ch = threadIdx.x;
  int j = q2k[sk];
  out_ksc[(size_t)sk*CA_+ch] = qsc[(size_t)j*CA_+ch];
  if (ch < 3) krp[sk*3+ch] = qrp[j*3+ch];
  if (ch == 0){
    out_kmask[sk] = qmask[j];
    kuid[sk] = uid[j];
  }
}

// ---- N3: fused QKV projection. Block = 16 rows, 128 threads (thread = out col).
//      W element loaded once per block, reused across 16 rows in registers. ----
__global__ __launch_bounds__(128) void n_qkv(
    const float* __restrict__ X, const float* __restrict__ wq, const float* __restrict__ wk,
    const float* __restrict__ wv, float* __restrict__ Qp, float* __restrict__ Kp, float* __restrict__ Vp)
{
  __shared__ float Xs[16*CA_];
  int tid = threadIdx.x;
  size_t r0 = (size_t)blockIdx.x * 16;
  for (int e = tid; e < 16*CA_; e += 128) Xs[e] = X[r0*CA_ + e];
  __syncthreads();
  int c = tid;
  float acc[16];

  #pragma unroll
  for (int r = 0; r < 16; ++r) acc[r] = 0.f;
  for (int i = 0; i < CA_; ++i){
    float w = wq[i*CA_+c];
    #pragma unroll
    for (int r = 0; r < 16; ++r) acc[r] += Xs[r*CA_+i] * w;
  }
  #pragma unroll
  for (int r = 0; r < 16; ++r) Qp[(r0+r)*CA_+c] = acc[r] * 0.17677669529663687f;

  #pragma unroll
  for (int r = 0; r < 16; ++r) acc[r] = 0.f;
  for (int i = 0; i < CA_; ++i){
    float w = wk[i*CA_+c];
    #pragma unroll
    for (int r = 0; r < 16; ++r) acc[r] += Xs[r*CA_+i] * w;
  }
  #pragma unroll
  for (int r = 0; r < 16; ++r) Kp[(r0+r)*CA_+c] = acc[r];

  #pragma unroll
  for (int r = 0; r < 16; ++r) acc[r] = 0.f;
  for (int i = 0; i < CA_; ++i){
    float w = wv[i*CA_+c];
    #pragma unroll
    for (int r = 0; r < 16; ++r) acc[r] += Xs[r*CA_+i] * w;
  }
  #pragma unroll
  for (int r = 0; r < 16; ++r) Vp[(r0+r)*CA_+c] = acc[r];
}

// ---- N4: 128->16 row-linear with relu on input ----
__global__ __launch_bounds__(128) void n_proj16(
    const float* __restrict__ X, const float* __restrict__ W, float* __restrict__ Y)
{
  int row = blockIdx.x*8 + (threadIdx.x >> 4);
  int c = threadIdx.x & 15;
  float acc = 0.f;
  for (int i = 0; i < CA_; ++i)
    acc += fmaxf(X[(size_t)row*CA_+i], 0.f) * W[i*CP_+c];
  Y[(size_t)row*CP_+c] = acc;
}

// ---- N5: pair conditioning + 3-layer MLP + bias. One block per (s,q), thread = k ----
__global__ __launch_bounds__(128) void n_pair(
    const int* __restrict__ q2k, const float* __restrict__ rowproj, const float* __restrict__ colproj,
    const float* __restrict__ qrp, const int* __restrict__ quid,
    const float* __restrict__ krp, const int* __restrict__ kuid,
    const float* __restrict__ w1, const float* __restrict__ w2, const float* __restrict__ w3,
    const float* __restrict__ wpo, const float* __restrict__ wpd, const float* __restrict__ wpv,
    const float* __restrict__ wb,
    float* __restrict__ out_pair, u16* __restrict__ bias_ws)
{
  __shared__ float w1s[256], w2s[256], w3s[256], wbs[64], wpos[48], wpds[16], wpvs[16];
  int tid = threadIdx.x;
  for (int e = tid; e < 256; e += 128){ w1s[e] = w1[e]; w2s[e] = w2[e]; w3s[e] = w3[e]; }
  if (tid < 64) wbs[tid] = wb[tid];
  if (tid < 48) wpos[tid] = wpo[tid];
  if (tid < 16){ wpds[tid] = wpd[tid]; wpvs[tid] = wpv[tid]; }
  __syncthreads();

  int sq = blockIdx.x;
  int s  = sq >> 5;
  int k  = tid;
  int sk = s*K_ + k;
  int j  = q2k[sk];

  float p[16];
  {
    float ox = qrp[sq*3+0] - krp[sk*3+0];
    float oy = qrp[sq*3+1] - krp[sk*3+1];
    float oz = qrp[sq*3+2] - krp[sk*3+2];
    float vf = (quid[sq] == kuid[sk]) ? 1.f : 0.f;
    float invd = vf / (1.f + ox*ox + oy*oy + oz*oz);
    #pragma unroll
    for (int c = 0; c < 16; ++c)
      p[c] = rowproj[(size_t)sq*CP_+c] + colproj[(size_t)j*CP_+c]
           + vf*(ox*wpos[c] + oy*wpos[16+c] + oz*wpos[32+c])
           + invd*wpds[c] + vf*wpvs[c];
  }
  float y[16];
  #pragma unroll
  for (int c = 0; c < 16; ++c) y[c] = 0.f;
  for (int i = 0; i < 16; ++i){
    float u = fmaxf(p[i], 0.f);
    #pragma unroll
    for (int c = 0; c < 16; ++c) y[c] += u * w1s[i*16+c];
  }
  float z[16];
  #pragma unroll
  for (int c = 0; c < 16; ++c) z[c] = 0.f;
  for (int i = 0; i < 16; ++i){
    float u = fmaxf(y[i], 0.f);
    #pragma unroll
    for (int c = 0; c < 16; ++c) z[c] += u * w2s[i*16+c];
  }
  for (int i = 0; i < 16; ++i){
    float u = fmaxf(z[i], 0.f);
    #pragma unroll
    for (int c = 0; c < 16; ++c) p[c] += u * w3s[i*16+c];
  }
  float b[4] = {0.f, 0.f, 0.f, 0.f};
  for (int c = 0; c < 16; ++c){
    #pragma unroll
    for (int h = 0; h < 4; ++h) b[h] += p[c] * wbs[c*4+h];
  }
  size_t rg = (size_t)sq*K_ + k;
  for (int c = 0; c < 16; ++c) out_pair[rg*16+c] = p[c];
  for (int h = 0; h < 4; ++h)  bias_ws[rg*4+h] = f2b(b[h]);
}

// ---- N6: attention. One 128-thread block per (s,h). K/V slices staged in LDS
//      (float4, pitch 36 floats: 16B-aligned + bank-spread; all compute reads are
//      intra-quarter broadcasts -> conflict-free). Thread = (q = t&31, kquarter = t>>5).
//      Scores live in registers; softmax combined via shfl_xor(32) + tiny LDS. ----
__global__ __launch_bounds__(128) void n_attn(
    const float* __restrict__ Qp, const float* __restrict__ Kp, const float* __restrict__ Vp,
    const float* __restrict__ qmask, const u16* __restrict__ bias_ws, const int* __restrict__ q2k,
    float* __restrict__ O)
{
  __shared__ float Ks[128*36];
  __shared__ float Vs[128*36];
  __shared__ float msk[128];
  __shared__ float redm[64];
  __shared__ float reds[64];
  __shared__ float Osm[32*33];

  int b = blockIdx.x;
  int s = b >> 2, h = b & 3;
  int sq0 = s * Q_;
  int base = s * K_;
  int t = threadIdx.x;

  // stage K,V slices: 128 rows x 32 dims, 8 float4 per row, 16 rows per sweep
  {
    int e = t & 7, rr = t >> 3;
    #pragma unroll
    for (int it = 0; it < 8; ++it){
      int row = it*16 + rr;
      int j = q2k[base + row];
      const float4* ksrc = (const float4*)&Kp[(size_t)j*CA_ + h*DH_];
      const float4* vsrc = (const float4*)&Vp[(size_t)j*CA_ + h*DH_];
      *(float4*)&Ks[row*36 + e*4] = ksrc[e];
      *(float4*)&Vs[row*36 + e*4] = vsrc[e];
    }
    int j0 = q2k[base + t];
    msk[t] = qmask[j0];
  }

  // Q row into registers (4 lanes share a row -> L1 broadcast)
  int q  = t & 31;
  int kr = t >> 5;
  float qreg[32];
  {
    const float4* qsrc = (const float4*)&Qp[(size_t)(sq0+q)*CA_ + h*DH_];
    #pragma unroll
    for (int d4 = 0; d4 < 8; ++d4){
      float4 v = qsrc[d4];
      qreg[d4*4+0] = v.x; qreg[d4*4+1] = v.y; qreg[d4*4+2] = v.z; qreg[d4*4+3] = v.w;
    }
  }
  __syncthreads();

  // QK^T for this thread's 32 keys
  float p[32];
  #pragma unroll
  for (int kk = 0; kk < 32; ++kk){
    int k = kr*32 + kk;
    const float* kbase = &Ks[k*36];
    float acc = 0.f;
    #pragma unroll
    for (int d4 = 0; d4 < 8; ++d4){
      float4 kv = *(const float4*)(kbase + d4*4);
      acc += qreg[d4*4+0]*kv.x + qreg[d4*4+1]*kv.y + qreg[d4*4+2]*kv.z + qreg[d4*4+3]*kv.w;
    }
    float bz = b2f(bias_ws[((size_t)(sq0+q)*K_ + k)*4 + h]);
    p[kk] = (msk[k] > 0.f) ? (acc + bz) : -1e9f;
  }

  // softmax: per-thread max/sum over 32 keys, combine quarters
  float m = p[0];
  #pragma unroll
  for (int kk = 1; kk < 32; ++kk) m = fmaxf(m, p[kk]);
  m = fmaxf(m, __shfl_xor(m, 32, 64));
  int wv = t >> 6;
  if ((t & 63) < 32) redm[wv*32 + q] = m;
  __syncthreads();
  float M = fmaxf(redm[q], redm[32 + q]);

  float sm = 0.f;
  #pragma unroll
  for (int kk = 0; kk < 32; ++kk){ p[kk] = __expf(p[kk] - M); sm += p[kk]; }
  sm += __shfl_xor(sm, 32, 64);
  if ((t & 63) < 32) reds[wv*32 + q] = sm;
  __syncthreads();
  float inv = 1.f / (reds[q] + reds[32 + q]);

  // PV partial over this thread's 32 keys
  float acc[32];
  #pragma unroll
  for (int d = 0; d < 32; ++d) acc[d] = 0.f;
  #pragma unroll
  for (int kk = 0; kk < 32; ++kk){
    float w = p[kk];
    const float* vbase = &Vs[(kr*32 + kk)*36];
    #pragma unroll
    for (int d4 = 0; d4 < 8; ++d4){
      float4 vv = *(const float4*)(vbase + d4*4);
      acc[d4*4+0] += w*vv.x; acc[d4*4+1] += w*vv.y; acc[d4*4+2] += w*vv.z; acc[d4*4+3] += w*vv.w;
    }
  }
  // combine quarter pairs within wave
  #pragma unroll
  for (int d = 0; d < 32; ++d) acc[d] += __shfl_xor(acc[d], 32, 64);
  // cross-wave combine via LDS
  if (t < 32){
    #pragma unroll
    for (int d = 0; d < 32; ++d) Osm[q*33 + d] = acc[d];
  }
  __syncthreads();
  if (t >= 64 && t < 96){
    #pragma unroll
    for (int d = 0; d < 32; ++d) Osm[q*33 + d] = (Osm[q*33 + d] + acc[d]) * inv;
  }
  __syncthreads();

  // coalesced float4 store of the 32x32 output slice
  #pragma unroll
  for (int it = 0; it < 2; ++it){
    int idx = it*128 + t;
    int qq = idx >> 3, e = idx & 7;
    float4 v = make_float4(Osm[qq*33 + e*4 + 0], Osm[qq*33 + e*4 + 1],
                           Osm[qq*33 + e*4 + 2], Osm[qq*33 + e*4 + 3]);
    *(float4*)&O[(size_t)(sq0+qq)*CA_ + h*DH_ + e*4] = v;
  }
}

// ---- N7: queries_act = (qsc + O @ wo) * qmask. Block = 16 rows, W reuse across rows ----
__global__ __launch_bounds__(128) void n_qact(
    const float* __restrict__ qsc, const float* __restrict__ O, const float* __restrict__ qmask,
    const float* __restrict__ wo, float* __restrict__ qact, float* __restrict__ out_skip)
{
  __shared__ float Os[16*CA_];
  int tid = threadIdx.x;
  size_t r0 = (size_t)blockIdx.x * 16;
  for (int e = tid; e < 16*CA_; e += 128) Os[e] = O[r0*CA_ + e];
  __syncthreads();
  int c = tid;
  float acc[16];
  #pragma unroll
  for (int r = 0; r < 16; ++r) acc[r] = 0.f;
  for (int i = 0; i < CA_; ++i){
    float w = wo[i*CA_+c];
    #pragma unroll
    for (int r = 0; r < 16; ++r) acc[r] += Os[r*CA_+i] * w;
  }
  #pragma unroll
  for (int r = 0; r < 16; ++r){
    float v = (qsc[(r0+r)*CA_+c] + acc[r]) * qmask[r0+r];
    qact[(r0+r)*CA_+c] = v;
    out_skip[(r0+r)*CA_+c] = v;
  }
}

// ---- N8: proj + gather + masked mean. Stage 24 gathered rows in LDS; loop channels
//      outer so each w_proj element is loaded once and reused 24x. ----
__global__ __launch_bounds__(384) void n_tok(
    const float* __restrict__ qact, const int* __restrict__ q2t, const float* __restrict__ amask,
    const float* __restrict__ wp, float* __restrict__ out_tok)
{
  __shared__ float Xs[D_*CA_];
  __shared__ int   jr[D_];
  __shared__ float mk[D_];
  int t = blockIdx.x, tid = threadIdx.x;
  if (tid < D_){
    jr[tid] = q2t[t*D_ + tid];
    mk[tid] = amask[t*D_ + tid];
  }
  __syncthreads();
  for (int e = tid; e < D_*CA_; e += 384){
    int d = e >> 7, i = e & 127;
    Xs[e] = qact[(size_t)jr[d]*CA_ + i];
  }
  __syncthreads();
  int ct = tid;
  float acc[D_];
  #pragma unroll
  for (int d = 0; d < D_; ++d) acc[d] = 0.f;
  for (int i = 0; i < CA_; ++i){
    float w = wp[i*CT_ + ct];
    #pragma unroll
    for (int d = 0; d < D_; ++d) acc[d] += Xs[d*CA_ + i] * w;
  }
  float num = 0.f, den = 1e-10f;
  #pragma unroll
  for (int d = 0; d < D_; ++d){
    num += mk[d] * fmaxf(acc[d], 0.f);
    den += mk[d];
  }
  out_tok[(size_t)t*CT_ + ct] = num/den;
}

extern "C" void kernel_launch(void* const* d_in, const int* in_sizes, int n_in,
                              void* d_out, int out_size, void* d_ws, size_t ws_size,
                              hipStream_t stream) {
  (void)in_sizes; (void)n_in; (void)out_size; (void)ws_size;
  const float* ref_positions = (const float*)d_in[0];
  const float* ref_mask      = (const float*)d_in[1];
  const float* ref_charge    = (const float*)d_in[2];
  const float* atom_mask     = (const float*)d_in[3];
  const int*   ref_element   = (const int*)d_in[4];
  const int*   ref_chars     = (const int*)d_in[5];
  const int*   ref_uid       = (const int*)d_in[6];
  const int*   t2q           = (const int*)d_in[7];
  const int*   q2k           = (const int*)d_in[8];
  const int*   q2t           = (const int*)d_in[9];
  const float* w_ref_pos     = (const float*)d_in[10];
  const float* w_ref_mask    = (const float*)d_in[11];
  const float* w_ref_element = (const float*)d_in[12];
  const float* w_ref_charge  = (const float*)d_in[13];
  const float* w_ref_name    = (const float*)d_in[14];
  const float* w_s2p_row1    = (const float*)d_in[15];
  const float* w_s2p_col1    = (const float*)d_in[16];
  const float* w_pair_off1   = (const float*)d_in[17];
  const float* w_pair_dist1  = (const float*)d_in[18];
  const float* w_pair_valid  = (const float*)d_in[19];
  const float* w_mlp1        = (const float*)d_in[20];
  const float* w_mlp2        = (const float*)d_in[21];
  const float* w_mlp3        = (const float*)d_in[22];
  const float* wq            = (const float*)d_in[23];
  const float* wk            = (const float*)d_in[24];
  const float* wv            = (const float*)d_in[25];
  const float* wb            = (const float*)d_in[26];
  const float* wo            = (const float*)d_in[27];
  const float* w_proj        = (const float*)d_in[28];

  char* ws = (char*)d_ws;
  float* qsc     = (float*)(ws + 0);
  float* qmask   = (float*)(ws + 9437184);
  float* qrp     = (float*)(ws + 9732096);
  int*   quid    = (int*)  (ws + 9953280);
  float* krp     = (float*)(ws + 10027008);
  int*   kuid    = (int*)  (ws + 10911744);
  float* rowproj = (float*)(ws + 11206656);
  float* colproj = (float*)(ws + 12386304);
  float* Qp      = (float*)(ws + 13565952);
  float* Kp      = (float*)(ws + 23003136);
  float* Vp      = (float*)(ws + 32440320);
  float* O       = (float*)(ws + 41877504);
  float* qact    = (float*)(ws + 51314688);
  u16*   biasws  = (u16*)  (ws + 60751872);

  float* out = (float*)d_out;
  float* out_tok   = out + 0;
  float* out_skip  = out + 294912;
  float* out_qmask = out + 2654208;
  float* out_qsc   = out + 2672640;
  float* out_kmask = out + 5031936;
  float* out_ksc   = out + 5105664;
  float* out_pair  = out + 14542848;

  hipLaunchKernelGGL(n_qsc, dim3(SQ_), dim3(128), 0, stream,
      ref_positions, ref_mask, ref_charge, atom_mask, ref_element, ref_chars, ref_uid, t2q,
      w_ref_pos, w_ref_mask, w_ref_element, w_ref_charge, w_ref_name,
      qsc, qmask, qrp, quid, out_qsc, out_qmask);
  hipLaunchKernelGGL(n_keys, dim3(SK_), dim3(128), 0, stream,
      qsc, qmask, qrp, ref_uid, q2k, krp, kuid, out_ksc, out_kmask);
  hipLaunchKernelGGL(n_qkv, dim3(SQ_/16), dim3(128), 0, stream,
      qsc, wq, wk, wv, Qp, Kp, Vp);
  hipLaunchKernelGGL(n_proj16, dim3(SQ_/8), dim3(128), 0, stream,
      qsc, w_s2p_row1, rowproj);
  hipLaunchKernelGGL(n_proj16, dim3(SQ_/8), dim3(128), 0, stream,
      qsc, w_s2p_col1, colproj);
  hipLaunchKernelGGL(n_pair, dim3(SQ_), dim3(128), 0, stream,
      q2k, rowproj, colproj, qrp, quid, krp, kuid,
      w_mlp1, w_mlp2, w_mlp3, w_pair_off1, w_pair_dist1, w_pair_valid, wb,
      out_pair, biasws);
  hipLaunchKernelGGL(n_attn, dim3(S_*H_), dim3(128), 0, stream,
      Qp, Kp, Vp, qmask, biasws, q2k, O);
  hipLaunchKernelGGL(n_qact, dim3(SQ_/16), dim3(128), 0, stream,
      qsc, O, qmask, wo, qact, out_skip);
  hipLaunchKernelGGL(n_tok, dim3(T_), dim3(384), 0, stream,
      qact, q2t, atom_mask, w_proj, out_tok);
}

// Round 2
// 596.498 us; speedup vs baseline: 1.6404x; 1.0303x over previous
//
#include <hip/hip_runtime.h>

typedef unsigned short u16;
typedef unsigned int u32;

#define T_ 768
#define D_ 24
#define S_ 576
#define Q_ 32
#define K_ 128
#define CA_ 128
#define CP_ 16
#define CT_ 384
#define H_ 4
#define DH_ 32
#define SQ_ (S_*Q_)
#define SK_ (S_*K_)

__device__ __forceinline__ float b2f(u16 u){ return __uint_as_float(((u32)u)<<16); }
__device__ __forceinline__ u16 f2b(float f){ u32 x=__float_as_uint(f); return (u16)((x + 0x7fffu + ((x>>16)&1u))>>16); }

// ---- N1: per-atom conditioning gathered to query slots; also qrp/quid ----
__global__ __launch_bounds__(128) void n_qsc(
    const float* __restrict__ pos, const float* __restrict__ rmask, const float* __restrict__ charge,
    const float* __restrict__ amask, const int* __restrict__ elem, const int* __restrict__ chars,
    const int* __restrict__ uid, const int* __restrict__ t2q,
    const float* __restrict__ w_pos, const float* __restrict__ w_mask, const float* __restrict__ w_elem,
    const float* __restrict__ w_chg, const float* __restrict__ w_name,
    float* __restrict__ qsc, float* __restrict__ qmask, float* __restrict__ qrp, int* __restrict__ quid,
    float* __restrict__ out_qsc, float* __restrict__ out_qmask)
{
  int slot = blockIdx.x, ch = threadIdx.x;
  int a = t2q[slot];
  float p0 = pos[a*3+0], p1 = pos[a*3+1], p2 = pos[a*3+2];
  float m  = rmask[a];
  float cg = asinhf(charge[a]);
  int e  = elem[a];
  int c0 = chars[a*4+0], c1 = chars[a*4+1], c2 = chars[a*4+2], c3 = chars[a*4+3];
  float v = p0*w_pos[0*CA_+ch] + p1*w_pos[1*CA_+ch] + p2*w_pos[2*CA_+ch];
  v += m * w_mask[ch];
  v += w_elem[e*CA_+ch];
  v += cg * w_chg[ch];
  v += w_name[(0*64+c0)*CA_+ch] + w_name[(1*64+c1)*CA_+ch]
     + w_name[(2*64+c2)*CA_+ch] + w_name[(3*64+c3)*CA_+ch];
  v *= m;
  qsc[(size_t)slot*CA_+ch] = v;
  out_qsc[(size_t)slot*CA_+ch] = v;
  if (ch < 3) qrp[slot*3+ch] = pos[a*3+ch];
  if (ch == 0){
    float am = amask[a];
    qmask[slot] = am;
    out_qmask[slot] = am;
    quid[slot] = uid[a];
  }
}

// ---- N2: key-space gathers. 4 rows/block, one float4 per thread ----
__global__ __launch_bounds__(128) void n_keys(
    const float* __restrict__ qsc, const float* __restrict__ qmask, const float* __restrict__ qrp,
    const int* __restrict__ uid, const int* __restrict__ q2k,
    float* __restrict__ krp, int* __restrict__ kuid,
    float* __restrict__ out_ksc, float* __restrict__ out_kmask)
{
  int r = threadIdx.x >> 5;
  int e = threadIdx.x & 31;
  int sk = blockIdx.x*4 + r;
  int j = q2k[sk];
  *(float4*)&out_ksc[(size_t)sk*CA_ + e*4] = *(const float4*)&qsc[(size_t)j*CA_ + e*4];
  if (e < 3) krp[sk*3+e] = qrp[j*3+e];
  if (e == 0){
    out_kmask[sk] = qmask[j];
    kuid[sk] = uid[j];
  }
}

// ---- N3: fused QKV projection. Block = 16 rows, 128 threads (thread = out col). ----
__global__ __launch_bounds__(128) void n_qkv(
    const float* __restrict__ X, const float* __restrict__ wq, const float* __restrict__ wk,
    const float* __restrict__ wv, float* __restrict__ Qp, float* __restrict__ Kp, float* __restrict__ Vp)
{
  __shared__ float Xs[16*CA_];
  int tid = threadIdx.x;
  size_t r0 = (size_t)blockIdx.x * 16;
  for (int e = tid; e < 16*CA_; e += 128) Xs[e] = X[r0*CA_ + e];
  __syncthreads();
  int c = tid;
  float acc[16];

  #pragma unroll
  for (int r = 0; r < 16; ++r) acc[r] = 0.f;
  for (int i = 0; i < CA_; ++i){
    float w = wq[i*CA_+c];
    #pragma unroll
    for (int r = 0; r < 16; ++r) acc[r] += Xs[r*CA_+i] * w;
  }
  #pragma unroll
  for (int r = 0; r < 16; ++r) Qp[(r0+r)*CA_+c] = acc[r] * 0.17677669529663687f;

  #pragma unroll
  for (int r = 0; r < 16; ++r) acc[r] = 0.f;
  for (int i = 0; i < CA_; ++i){
    float w = wk[i*CA_+c];
    #pragma unroll
    for (int r = 0; r < 16; ++r) acc[r] += Xs[r*CA_+i] * w;
  }
  #pragma unroll
  for (int r = 0; r < 16; ++r) Kp[(r0+r)*CA_+c] = acc[r];

  #pragma unroll
  for (int r = 0; r < 16; ++r) acc[r] = 0.f;
  for (int i = 0; i < CA_; ++i){
    float w = wv[i*CA_+c];
    #pragma unroll
    for (int r = 0; r < 16; ++r) acc[r] += Xs[r*CA_+i] * w;
  }
  #pragma unroll
  for (int r = 0; r < 16; ++r) Vp[(r0+r)*CA_+c] = acc[r];
}

// ---- N4: fused row+col 128->16 relu-linear. Block = 4 rows x 32 cols (16 row, 16 col) ----
__global__ __launch_bounds__(128) void n_proj16b(
    const float* __restrict__ X, const float* __restrict__ Wr, const float* __restrict__ Wc,
    float* __restrict__ Yr, float* __restrict__ Yc)
{
  int row = blockIdx.x*4 + (threadIdx.x >> 5);
  int c = threadIdx.x & 31;
  const float* W = (c < 16) ? Wr : Wc;
  float* Y = (c < 16) ? Yr : Yc;
  int cc = c & 15;
  float acc = 0.f;
  for (int i = 0; i < CA_; ++i)
    acc += fmaxf(X[(size_t)row*CA_+i], 0.f) * W[i*CP_+cc];
  Y[(size_t)row*CP_+cc] = acc;
}

// ---- N5: pair conditioning + 3-layer MLP + bias. One block per (s,q), thread = k.
//      out_pair written via LDS transpose -> fully coalesced float4 stores.
//      bias written in [s][h][q][k] layout -> coalesced 2B stores, contiguous reads in attn. ----
__global__ __launch_bounds__(128) void n_pair(
    const int* __restrict__ q2k, const float* __restrict__ rowproj, const float* __restrict__ colproj,
    const float* __restrict__ qrp, const int* __restrict__ quid,
    const float* __restrict__ krp, const int* __restrict__ kuid,
    const float* __restrict__ w1, const float* __restrict__ w2, const float* __restrict__ w3,
    const float* __restrict__ wpo, const float* __restrict__ wpd, const float* __restrict__ wpv,
    const float* __restrict__ wb,
    float* __restrict__ out_pair, u16* __restrict__ bias_ws)
{
  __shared__ float w1s[256], w2s[256], w3s[256], wbs[64], wpos[48], wpds[16], wpvs[16];
  __shared__ __align__(16) float Ls[128*20];   // pitch 20 floats: 16B-aligned rows, bank-spread
  int tid = threadIdx.x;
  for (int e = tid; e < 256; e += 128){ w1s[e] = w1[e]; w2s[e] = w2[e]; w3s[e] = w3[e]; }
  if (tid < 64) wbs[tid] = wb[tid];
  if (tid < 48) wpos[tid] = wpo[tid];
  if (tid < 16){ wpds[tid] = wpd[tid]; wpvs[tid] = wpv[tid]; }
  __syncthreads();

  int sq = blockIdx.x;
  int s  = sq >> 5;
  int q  = sq & 31;
  int k  = tid;
  int sk = s*K_ + k;
  int j  = q2k[sk];

  float rp[16], cp[16];
  *(float4*)&rp[0]  = *(const float4*)&rowproj[(size_t)sq*CP_ + 0];
  *(float4*)&rp[4]  = *(const float4*)&rowproj[(size_t)sq*CP_ + 4];
  *(float4*)&rp[8]  = *(const float4*)&rowproj[(size_t)sq*CP_ + 8];
  *(float4*)&rp[12] = *(const float4*)&rowproj[(size_t)sq*CP_ + 12];
  *(float4*)&cp[0]  = *(const float4*)&colproj[(size_t)j*CP_ + 0];
  *(float4*)&cp[4]  = *(const float4*)&colproj[(size_t)j*CP_ + 4];
  *(float4*)&cp[8]  = *(const float4*)&colproj[(size_t)j*CP_ + 8];
  *(float4*)&cp[12] = *(const float4*)&colproj[(size_t)j*CP_ + 12];

  float p[16];
  {
    float ox = qrp[sq*3+0] - krp[sk*3+0];
    float oy = qrp[sq*3+1] - krp[sk*3+1];
    float oz = qrp[sq*3+2] - krp[sk*3+2];
    float vf = (quid[sq] == kuid[sk]) ? 1.f : 0.f;
    float invd = vf / (1.f + ox*ox + oy*oy + oz*oz);
    #pragma unroll
    for (int c = 0; c < 16; ++c)
      p[c] = rp[c] + cp[c]
           + vf*(ox*wpos[c] + oy*wpos[16+c] + oz*wpos[32+c])
           + invd*wpds[c] + vf*wpvs[c];
  }
  float y[16];
  #pragma unroll
  for (int c = 0; c < 16; ++c) y[c] = 0.f;
  for (int i = 0; i < 16; ++i){
    float u = fmaxf(p[i], 0.f);
    #pragma unroll
    for (int c = 0; c < 16; ++c) y[c] += u * w1s[i*16+c];
  }
  float z[16];
  #pragma unroll
  for (int c = 0; c < 16; ++c) z[c] = 0.f;
  for (int i = 0; i < 16; ++i){
    float u = fmaxf(y[i], 0.f);
    #pragma unroll
    for (int c = 0; c < 16; ++c) z[c] += u * w2s[i*16+c];
  }
  for (int i = 0; i < 16; ++i){
    float u = fmaxf(z[i], 0.f);
    #pragma unroll
    for (int c = 0; c < 16; ++c) p[c] += u * w3s[i*16+c];
  }
  float b[4] = {0.f, 0.f, 0.f, 0.f};
  for (int c = 0; c < 16; ++c){
    #pragma unroll
    for (int h = 0; h < 4; ++h) b[h] += p[c] * wbs[c*4+h];
  }

  // bias: [s][h][q][k] layout, lanes contiguous over k -> 4x coalesced 256B stores
  #pragma unroll
  for (int h = 0; h < 4; ++h)
    bias_ws[(((size_t)s*H_ + h)*Q_ + q)*K_ + k] = f2b(b[h]);

  // out_pair: transpose through LDS, then fully coalesced float4 stores
  #pragma unroll
  for (int c4 = 0; c4 < 4; ++c4)
    *(float4*)&Ls[k*20 + c4*4] = make_float4(p[c4*4+0], p[c4*4+1], p[c4*4+2], p[c4*4+3]);
  __syncthreads();
  size_t obase = (size_t)sq * (K_*CP_);
  #pragma unroll
  for (int i = 0; i < 4; ++i){
    int g4 = i*128 + tid;           // float4 index within the 8KB block span
    int kk = g4 >> 2, c = (g4 & 3)*4;
    *(float4*)&out_pair[obase + (size_t)g4*4] = *(const float4*)&Ls[kk*20 + c];
  }
}

// ---- N6: attention. One 128-thread block per (s,h). K/V staged in LDS (pitch 36).
//      Thread = (q = t&31, kquarter = t>>5). Bias read contiguous (new layout). ----
__global__ __launch_bounds__(128) void n_attn(
    const float* __restrict__ Qp, const float* __restrict__ Kp, const float* __restrict__ Vp,
    const float* __restrict__ qmask, const u16* __restrict__ bias_ws, const int* __restrict__ q2k,
    float* __restrict__ O)
{
  __shared__ float Ks[128*36];
  __shared__ float Vs[128*36];
  __shared__ float msk[128];
  __shared__ float redm[64];
  __shared__ float reds[64];
  __shared__ float Osm[32*33];

  int b = blockIdx.x;
  int s = b >> 2, h = b & 3;
  int sq0 = s * Q_;
  int base = s * K_;
  int t = threadIdx.x;

  // stage K,V slices: 128 rows x 32 dims, 8 float4 per row, 16 rows per sweep
  {
    int e = t & 7, rr = t >> 3;
    #pragma unroll
    for (int it = 0; it < 8; ++it){
      int row = it*16 + rr;
      int j = q2k[base + row];
      const float4* ksrc = (const float4*)&Kp[(size_t)j*CA_ + h*DH_];
      const float4* vsrc = (const float4*)&Vp[(size_t)j*CA_ + h*DH_];
      *(float4*)&Ks[row*36 + e*4] = ksrc[e];
      *(float4*)&Vs[row*36 + e*4] = vsrc[e];
    }
    int j0 = q2k[base + t];
    msk[t] = qmask[j0];
  }

  int q  = t & 31;
  int kr = t >> 5;
  float qreg[32];
  {
    const float4* qsrc = (const float4*)&Qp[(size_t)(sq0+q)*CA_ + h*DH_];
    #pragma unroll
    for (int d4 = 0; d4 < 8; ++d4){
      float4 v = qsrc[d4];
      qreg[d4*4+0] = v.x; qreg[d4*4+1] = v.y; qreg[d4*4+2] = v.z; qreg[d4*4+3] = v.w;
    }
  }

  // bias: 32 u16 = 64B contiguous per thread
  u32 bw[16];
  {
    const uint4* bsrc = (const uint4*)&bias_ws[(((size_t)s*H_ + h)*Q_ + q)*K_ + kr*32];
    uint4 B;
    B = bsrc[0]; bw[0]=B.x;  bw[1]=B.y;  bw[2]=B.z;  bw[3]=B.w;
    B = bsrc[1]; bw[4]=B.x;  bw[5]=B.y;  bw[6]=B.z;  bw[7]=B.w;
    B = bsrc[2]; bw[8]=B.x;  bw[9]=B.y;  bw[10]=B.z; bw[11]=B.w;
    B = bsrc[3]; bw[12]=B.x; bw[13]=B.y; bw[14]=B.z; bw[15]=B.w;
  }
  __syncthreads();

  // QK^T for this thread's 32 keys
  float p[32];
  #pragma unroll
  for (int kk = 0; kk < 32; ++kk){
    int k = kr*32 + kk;
    const float* kbase = &Ks[k*36];
    float acc = 0.f;
    #pragma unroll
    for (int d4 = 0; d4 < 8; ++d4){
      float4 kv = *(const float4*)(kbase + d4*4);
      acc += qreg[d4*4+0]*kv.x + qreg[d4*4+1]*kv.y + qreg[d4*4+2]*kv.z + qreg[d4*4+3]*kv.w;
    }
    float bz = b2f((u16)((bw[kk>>1] >> ((kk&1)*16)) & 0xffffu));
    p[kk] = (msk[k] > 0.f) ? (acc + bz) : -1e9f;
  }

  // softmax: per-thread max/sum over 32 keys, combine quarters
  float m = p[0];
  #pragma unroll
  for (int kk = 1; kk < 32; ++kk) m = fmaxf(m, p[kk]);
  m = fmaxf(m, __shfl_xor(m, 32, 64));
  int wv = t >> 6;
  if ((t & 63) < 32) redm[wv*32 + q] = m;
  __syncthreads();
  float M = fmaxf(redm[q], redm[32 + q]);

  float sm = 0.f;
  #pragma unroll
  for (int kk = 0; kk < 32; ++kk){ p[kk] = __expf(p[kk] - M); sm += p[kk]; }
  sm += __shfl_xor(sm, 32, 64);
  if ((t & 63) < 32) reds[wv*32 + q] = sm;
  __syncthreads();
  float inv = 1.f / (reds[q] + reds[32 + q]);

  // PV partial over this thread's 32 keys
  float acc[32];
  #pragma unroll
  for (int d = 0; d < 32; ++d) acc[d] = 0.f;
  #pragma unroll
  for (int kk = 0; kk < 32; ++kk){
    float w = p[kk];
    const float* vbase = &Vs[(kr*32 + kk)*36];
    #pragma unroll
    for (int d4 = 0; d4 < 8; ++d4){
      float4 vv = *(const float4*)(vbase + d4*4);
      acc[d4*4+0] += w*vv.x; acc[d4*4+1] += w*vv.y; acc[d4*4+2] += w*vv.z; acc[d4*4+3] += w*vv.w;
    }
  }
  #pragma unroll
  for (int d = 0; d < 32; ++d) acc[d] += __shfl_xor(acc[d], 32, 64);
  if (t < 32){
    #pragma unroll
    for (int d = 0; d < 32; ++d) Osm[q*33 + d] = acc[d];
  }
  __syncthreads();
  if (t >= 64 && t < 96){
    #pragma unroll
    for (int d = 0; d < 32; ++d) Osm[q*33 + d] = (Osm[q*33 + d] + acc[d]) * inv;
  }
  __syncthreads();

  #pragma unroll
  for (int it = 0; it < 2; ++it){
    int idx = it*128 + t;
    int qq = idx >> 3, e = idx & 7;
    float4 v = make_float4(Osm[qq*33 + e*4 + 0], Osm[qq*33 + e*4 + 1],
                           Osm[qq*33 + e*4 + 2], Osm[qq*33 + e*4 + 3]);
    *(float4*)&O[(size_t)(sq0+qq)*CA_ + h*DH_ + e*4] = v;
  }
}

// ---- N7: queries_act = (qsc + O @ wo) * qmask. Block = 16 rows, W reuse across rows ----
__global__ __launch_bounds__(128) void n_qact(
    const float* __restrict__ qsc, const float* __restrict__ O, const float* __restrict__ qmask,
    const float* __restrict__ wo, float* __restrict__ qact, float* __restrict__ out_skip)
{
  __shared__ float Os[16*CA_];
  int tid = threadIdx.x;
  size_t r0 = (size_t)blockIdx.x * 16;
  for (int e = tid; e < 16*CA_; e += 128) Os[e] = O[r0*CA_ + e];
  __syncthreads();
  int c = tid;
  float acc[16];
  #pragma unroll
  for (int r = 0; r < 16; ++r) acc[r] = 0.f;
  for (int i = 0; i < CA_; ++i){
    float w = wo[i*CA_+c];
    #pragma unroll
    for (int r = 0; r < 16; ++r) acc[r] += Os[r*CA_+i] * w;
  }
  #pragma unroll
  for (int r = 0; r < 16; ++r){
    float v = (qsc[(r0+r)*CA_+c] + acc[r]) * qmask[r0+r];
    qact[(r0+r)*CA_+c] = v;
    out_skip[(r0+r)*CA_+c] = v;
  }
}

// ---- N8: proj + gather + masked mean ----
__global__ __launch_bounds__(384) void n_tok(
    const float* __restrict__ qact, const int* __restrict__ q2t, const float* __restrict__ amask,
    const float* __restrict__ wp, float* __restrict__ out_tok)
{
  __shared__ float Xs[D_*CA_];
  __shared__ int   jr[D_];
  __shared__ float mk[D_];
  int t = blockIdx.x, tid = threadIdx.x;
  if (tid < D_){
    jr[tid] = q2t[t*D_ + tid];
    mk[tid] = amask[t*D_ + tid];
  }
  __syncthreads();
  for (int e = tid; e < D_*CA_; e += 384){
    int d = e >> 7, i = e & 127;
    Xs[e] = qact[(size_t)jr[d]*CA_ + i];
  }
  __syncthreads();
  int ct = tid;
  float acc[D_];
  #pragma unroll
  for (int d = 0; d < D_; ++d) acc[d] = 0.f;
  for (int i = 0; i < CA_; ++i){
    float w = wp[i*CT_ + ct];
    #pragma unroll
    for (int d = 0; d < D_; ++d) acc[d] += Xs[d*CA_ + i] * w;
  }
  float num = 0.f, den = 1e-10f;
  #pragma unroll
  for (int d = 0; d < D_; ++d){
    num += mk[d] * fmaxf(acc[d], 0.f);
    den += mk[d];
  }
  out_tok[(size_t)t*CT_ + ct] = num/den;
}

extern "C" void kernel_launch(void* const* d_in, const int* in_sizes, int n_in,
                              void* d_out, int out_size, void* d_ws, size_t ws_size,
                              hipStream_t stream) {
  (void)in_sizes; (void)n_in; (void)out_size; (void)ws_size;
  const float* ref_positions = (const float*)d_in[0];
  const float* ref_mask      = (const float*)d_in[1];
  const float* ref_charge    = (const float*)d_in[2];
  const float* atom_mask     = (const float*)d_in[3];
  const int*   ref_element   = (const int*)d_in[4];
  const int*   ref_chars     = (const int*)d_in[5];
  const int*   ref_uid       = (const int*)d_in[6];
  const int*   t2q           = (const int*)d_in[7];
  const int*   q2k           = (const int*)d_in[8];
  const int*   q2t           = (const int*)d_in[9];
  const float* w_ref_pos     = (const float*)d_in[10];
  const float* w_ref_mask    = (const float*)d_in[11];
  const float* w_ref_element = (const float*)d_in[12];
  const float* w_ref_charge  = (const float*)d_in[13];
  const float* w_ref_name    = (const float*)d_in[14];
  const float* w_s2p_row1    = (const float*)d_in[15];
  const float* w_s2p_col1    = (const float*)d_in[16];
  const float* w_pair_off1   = (const float*)d_in[17];
  const float* w_pair_dist1  = (const float*)d_in[18];
  const float* w_pair_valid  = (const float*)d_in[19];
  const float* w_mlp1        = (const float*)d_in[20];
  const float* w_mlp2        = (const float*)d_in[21];
  const float* w_mlp3        = (const float*)d_in[22];
  const float* wq            = (const float*)d_in[23];
  const float* wk            = (const float*)d_in[24];
  const float* wv            = (const float*)d_in[25];
  const float* wb            = (const float*)d_in[26];
  const float* wo            = (const float*)d_in[27];
  const float* w_proj        = (const float*)d_in[28];

  char* ws = (char*)d_ws;
  float* qsc     = (float*)(ws + 0);
  float* qmask   = (float*)(ws + 9437184);
  float* qrp     = (float*)(ws + 9732096);
  int*   quid    = (int*)  (ws + 9953280);
  float* krp     = (float*)(ws + 10027008);
  int*   kuid    = (int*)  (ws + 10911744);
  float* rowproj = (float*)(ws + 11206656);
  float* colproj = (float*)(ws + 12386304);
  float* Qp      = (float*)(ws + 13565952);
  float* Kp      = (float*)(ws + 23003136);
  float* Vp      = (float*)(ws + 32440320);
  float* O       = (float*)(ws + 41877504);
  float* qact    = (float*)(ws + 51314688);
  u16*   biasws  = (u16*)  (ws + 60751872);

  float* out = (float*)d_out;
  float* out_tok   = out + 0;
  float* out_skip  = out + 294912;
  float* out_qmask = out + 2654208;
  float* out_qsc   = out + 2672640;
  float* out_kmask = out + 5031936;
  float* out_ksc   = out + 5105664;
  float* out_pair  = out + 14542848;

  hipLaunchKernelGGL(n_qsc, dim3(SQ_), dim3(128), 0, stream,
      ref_positions, ref_mask, ref_charge, atom_mask, ref_element, ref_chars, ref_uid, t2q,
      w_ref_pos, w_ref_mask, w_ref_element, w_ref_charge, w_ref_name,
      qsc, qmask, qrp, quid, out_qsc, out_qmask);
  hipLaunchKernelGGL(n_keys, dim3(SK_/4), dim3(128), 0, stream,
      qsc, qmask, qrp, ref_uid, q2k, krp, kuid, out_ksc, out_kmask);
  hipLaunchKernelGGL(n_qkv, dim3(SQ_/16), dim3(128), 0, stream,
      qsc, wq, wk, wv, Qp, Kp, Vp);
  hipLaunchKernelGGL(n_proj16b, dim3(SQ_/4), dim3(128), 0, stream,
      qsc, w_s2p_row1, w_s2p_col1, rowproj, colproj);
  hipLaunchKernelGGL(n_pair, dim3(SQ_), dim3(128), 0, stream,
      q2k, rowproj, colproj, qrp, quid, krp, kuid,
      w_mlp1, w_mlp2, w_mlp3, w_pair_off1, w_pair_dist1, w_pair_valid, wb,
      out_pair, biasws);
  hipLaunchKernelGGL(n_attn, dim3(S_*H_), dim3(128), 0, stream,
      Qp, Kp, Vp, qmask, biasws, q2k, O);
  hipLaunchKernelGGL(n_qact, dim3(SQ_/16), dim3(128), 0, stream,
      qsc, O, qmask, wo, qact, out_skip);
  hipLaunchKernelGGL(n_tok, dim3(T_), dim3(384), 0, stream,
      qact, q2t, atom_mask, w_proj, out_tok);
}